// Round 2
// 298.391 us; speedup vs baseline: 1.0730x; 1.0730x over previous
//
#include <hip/hip_runtime.h>
#include <hip/hip_bf16.h>
#include <stdint.h>

// Problem constants
#define B_ 64
#define T_ 512
#define H_ 256
#define D_ 512
#define MS_ 64
#define ML_ 8
#define NST_ 64

typedef unsigned short u16;
typedef __bf16 bf8 __attribute__((ext_vector_type(8)));
typedef float f4 __attribute__((ext_vector_type(4)));

__device__ __forceinline__ u16 f2bf(float f) {
    unsigned u = __builtin_bit_cast(unsigned, f);
    u += 0x7fffu + ((u >> 16) & 1u);   // round-to-nearest-even
    return (u16)(u >> 16);
}
__device__ __forceinline__ float bf2f(u16 v) {
    return __builtin_bit_cast(float, (unsigned)v << 16);
}
__device__ __forceinline__ float sigm(float x) { return 1.f / (1.f + __expf(-x)); }

// ---------------- prep kernels ----------------
// Gate-interleaved column reorder: reordered col n (0..1023):
//   tile c = n>>6, nn = n&63, gate = nn>>4, jo = nn&15, j = c*16+jo,
//   orig_row = gate*256 + j.
// wcx[dir][n][k<512] = W_ih[orig][k]  (bf16)
// wch[dir][n][k<256] = W_hh[orig][k]  (bf16)
// bc [dir][n]        = bias[orig]     (f32)
__global__ __launch_bounds__(256) void build_wc2(const float* __restrict__ wihf,
                                                 const float* __restrict__ whhf,
                                                 const float* __restrict__ wihb,
                                                 const float* __restrict__ whhb,
                                                 const float* __restrict__ bf,
                                                 const float* __restrict__ bb,
                                                 u16* __restrict__ wcx,
                                                 u16* __restrict__ wch,
                                                 float* __restrict__ bc) {
    int i = blockIdx.x * 256 + threadIdx.x;
    if (i < 2 * 1024 * 768) {
        int dir = i / (1024 * 768);
        int rem = i - dir * 1024 * 768;
        int n = rem / 768;
        int k = rem - n * 768;
        int nn = n & 63, c = n >> 6;
        int orig = (nn >> 4) * 256 + c * 16 + (nn & 15);
        if (k < 512) {
            const float* wih = dir ? wihb : wihf;
            wcx[((size_t)dir * 1024 + n) * 512 + k] = f2bf(wih[orig * 512 + k]);
        } else {
            const float* whh = dir ? whhb : whhf;
            wch[((size_t)dir * 1024 + n) * 256 + (k - 512)] = f2bf(whh[orig * 256 + (k - 512)]);
        }
    } else if (i < 2 * 1024 * 768 + 2048) {
        int i2 = i - 2 * 1024 * 768;
        int dir = i2 >> 10;
        int n = i2 & 1023;
        int nn = n & 63, c = n >> 6;
        int orig = (nn >> 4) * 256 + c * 16 + (nn & 15);
        bc[i2] = (dir ? bb : bf)[orig];
    }
}

__global__ __launch_bounds__(256) void zero_ws(uint4* __restrict__ dst, int n4) {
    int i = blockIdx.x * 256 + threadIdx.x;
    if (i < n4) { uint4 z = {0u, 0u, 0u, 0u}; dst[i] = z; }
}

// ---------------- span packing (parallel, 1 block/row, 1 thread/token) -------
__global__ __launch_bounds__(512) void pack_spans2(const int* __restrict__ bio,
                                                   int* __restrict__ tok,
                                                   int* __restrict__ lenb) {
    __shared__ int wsum[8];
    __shared__ int start_s[64];
    __shared__ int len_s[64];
    int b = blockIdx.x;
    int t = threadIdx.x;
    int lane = t & 63, w = t >> 6;
    int v = bio[b * T_ + t];
    int bm = (v == 1);
    int im = (v == 2);
    if (t < 64) len_s[t] = 0;

    // scan 1: inclusive cumsum of bm
    int x = bm;
#pragma unroll
    for (int off = 1; off < 64; off <<= 1) {
        int y = __shfl_up(x, off, 64);
        if (lane >= off) x += y;
    }
    if (lane == 63) wsum[w] = x;
    __syncthreads();
    int wof = 0;
    for (int i = 0; i < w; ++i) wof += wsum[i];
    int sid = x + wof - 1;
    int valid = ((bm | im) && sid >= 0) ? 1 : 0;
    __syncthreads();           // wsum reuse

    // scan 2: inclusive cumsum of valid
    x = valid;
#pragma unroll
    for (int off = 1; off < 64; off <<= 1) {
        int y = __shfl_up(x, off, 64);
        if (lane >= off) x += y;
    }
    if (lane == 63) wsum[w] = x;
    __syncthreads();
    wof = 0;
    for (int i = 0; i < w; ++i) wof += wsum[i];
    int cs = x + wof;

    if (bm && sid < MS_) start_s[sid] = cs;   // B token: cs here == start -> rank 0
    __syncthreads();

    if (valid && sid < MS_) {
        int rank = cs - start_s[sid];
        if (rank < ML_) {
            tok[(b * MS_ + sid) * ML_ + rank] = t;
            atomicAdd(&len_s[sid], 1);
        }
    }
    __syncthreads();
    if (t < 64) lenb[b * MS_ + t] = len_s[t];
}

// Per-step compacted active-span lists. One block, 16 spans/thread.
__global__ __launch_bounds__(256) void build_lists(const int* __restrict__ lenb,
                                                   int* __restrict__ lists,
                                                   int* __restrict__ counts) {
    __shared__ int wsum[4];
    int tid = threadIdx.x;
    int lane = tid & 63, w = tid >> 6;
    int len[16];
#pragma unroll
    for (int i = 0; i < 16; ++i) len[i] = lenb[tid * 16 + i];
    for (int p = 0; p < ML_; ++p) {
        int c = 0;
#pragma unroll
        for (int i = 0; i < 16; ++i) c += (len[i] > p) ? 1 : 0;
        int x = c;
#pragma unroll
        for (int off = 1; off < 64; off <<= 1) {
            int y = __shfl_up(x, off, 64);
            if (lane >= off) x += y;
        }
        if (lane == 63) wsum[w] = x;
        __syncthreads();
        int wof = 0;
        for (int i = 0; i < w; ++i) wof += wsum[i];
        int pos = wof + x - c;                 // exclusive prefix
#pragma unroll
        for (int i = 0; i < 16; ++i)
            if (len[i] > p) lists[p * 4096 + pos++] = tid * 16 + i;
        if (tid == 255) counts[p] = pos;       // = grand total
        __syncthreads();
    }
}

// Gather-convert only the tokens spans actually use: xg[span*8+rank][512] bf16.
__global__ __launch_bounds__(64) void conv_gather(const float* __restrict__ repr,
                                                  const int* __restrict__ tok,
                                                  const int* __restrict__ lenb,
                                                  u16* __restrict__ xg) {
    int sr = blockIdx.x;            // span*8 + rank
    int span = sr >> 3, rank = sr & 7;
    if (rank >= lenb[span]) return;
    int t = tok[sr];
    int b = span >> 6;
    const float4* src = (const float4*)(repr + (size_t)(b * T_ + t) * D_);
    ushort4* dst = (ushort4*)(xg + (size_t)sr * D_);
    int i = threadIdx.x;            // 8 elems each
    float4 v0 = src[i * 2], v1 = src[i * 2 + 1];
    ushort4 o0, o1;
    o0.x = f2bf(v0.x); o0.y = f2bf(v0.y); o0.z = f2bf(v0.z); o0.w = f2bf(v0.w);
    o1.x = f2bf(v1.x); o1.y = f2bf(v1.y); o1.z = f2bf(v1.z); o1.w = f2bf(v1.w);
    dst[i * 2] = o0; dst[i * 2 + 1] = o1;
}

// ---------------- x-gate precompute GEMM (parallel, no recurrence) ----------
// For each (dir, p, list-idx): row = xg[span, rank(dir,p)] (K=512),
// B = wcx[dir] (N=1024 reordered). Output (+bias) stored bf16 in FRAGMENT
// ORDER: xgates[(blockIdx.y*16 + blockIdx.x)*4096 + tid*16 + nt*4 + r].
// Grid: x=16 n-tiles, y = (dir*8+p)*64 + rowblock (1024).
__global__ __launch_bounds__(256) void xgate_gemm(const u16* __restrict__ xg,
                                                  const u16* __restrict__ wcx,
                                                  const float* __restrict__ bc,
                                                  const int* __restrict__ lists,
                                                  const int* __restrict__ counts,
                                                  const int* __restrict__ lenb,
                                                  u16* __restrict__ xgates) {
    int gp = blockIdx.y >> 6;       // dir*8 + p
    int dir = gp >> 3, p = gp & 7;
    int rbk = blockIdx.y & 63;
    int cnt = counts[p];
    int base = rbk * 64;
    if (base >= cnt) return;
    int tid = threadIdx.x;

    __shared__ unsigned xoffs[64];
    __shared__ u16 As[64 * 72];
    __shared__ u16 Bs[64 * 72];

    if (tid < 64) {
        unsigned xo = 0;
        int idx = base + tid;
        if (idx < cnt) {
            int span = lists[p * 4096 + idx];
            int L = lenb[span];
            int rank = dir ? (L - 1 - p) : p;
            xo = (unsigned)(span * ML_ + rank) * D_;
        }
        xoffs[tid] = xo;
    }
    __syncthreads();

    int lane = tid & 63;
    int w16 = (tid >> 6) * 16;
    int mr = lane & 15;
    int q = lane >> 4;
    int q8 = q * 8;
    int n0 = blockIdx.x * 64;
    const u16* wb = wcx + (size_t)dir * 1024 * 512;

    f4 acc[4];
    f4 zed = {0.f, 0.f, 0.f, 0.f};
#pragma unroll
    for (int i = 0; i < 4; ++i) acc[i] = zed;

    for (int kt = 0; kt < 8; ++kt) {
#pragma unroll
        for (int i = 0; i < 2; ++i) {
            int c = tid + i * 256;
            int row = c >> 3;
            int cc = (c & 7) * 8;
            *(uint4*)&As[row * 72 + cc] = *(const uint4*)(xg + xoffs[row] + kt * 64 + cc);
            *(uint4*)&Bs[row * 72 + cc] =
                *(const uint4*)(wb + (size_t)(n0 + row) * 512 + kt * 64 + cc);
        }
        __syncthreads();
#pragma unroll
        for (int kk = 0; kk < 64; kk += 32) {
            bf8 af = *(const bf8*)&As[(w16 + mr) * 72 + kk + q8];
#pragma unroll
            for (int nt = 0; nt < 4; ++nt) {
                bf8 bg = *(const bf8*)&Bs[(nt * 16 + mr) * 72 + kk + q8];
                acc[nt] = __builtin_amdgcn_mfma_f32_16x16x32_bf16(af, bg, acc[nt], 0, 0, 0);
            }
        }
        __syncthreads();
    }

    // epilogue: + bias, bf16, fragment-order coalesced write
    u16 tmp[16];
#pragma unroll
    for (int nt = 0; nt < 4; ++nt)
#pragma unroll
        for (int r = 0; r < 4; ++r) {
            int n = n0 + nt * 16 + mr;
            tmp[nt * 4 + r] = f2bf(acc[nt][r] + bc[dir * 1024 + n]);
        }
    size_t off = ((size_t)blockIdx.y * 16 + blockIdx.x) * 4096 + (size_t)tid * 16;
    *(uint4*)&xgates[off] = *(const uint4*)tmp;
    *(uint4*)&xgates[off + 8] = *(const uint4*)(tmp + 8);
}

// ---------------- fused recurrent step: h@Whh GEMM + LSTM pointwise ----------
// K=256 only. acc initialized from precomputed xgates (bias folded).
// Gate-interleaved columns => thread (mr) holds all 4 gates of j = bx*16+mr
// across nt for 4 rows => pointwise is thread-local in the epilogue.
// h double-buffered (hin read, hout written) to avoid inter-block races.
__global__ __launch_bounds__(256) void fused_step(const u16* __restrict__ xgates,
                                                  const u16* __restrict__ hin,
                                                  u16* __restrict__ hout,
                                                  const u16* __restrict__ wch,
                                                  const int* __restrict__ lists,
                                                  const int* __restrict__ counts,
                                                  float* __restrict__ cbuf,
                                                  float* __restrict__ pooled, int p) {
    int cnt = counts[p];
    int rb = blockIdx.y;            // 0..127 ; 0..63 fwd, 64..127 bwd
    int dir = rb >> 6;
    int base = (rb & 63) * 64;
    if (base >= cnt) return;
    int tid = threadIdx.x;

    __shared__ unsigned hoffs[64];
    __shared__ int spans_s[64];
    __shared__ u16 As[64 * 72];
    __shared__ u16 Bs[64 * 72];

    if (tid < 64) {
        int span = 0;
        int idx = base + tid;
        if (idx < cnt) span = lists[p * 4096 + idx];
        spans_s[tid] = span;
        hoffs[tid] = (unsigned)(dir * 4096 + span) * H_;
    }
    __syncthreads();

    int lane = tid & 63;
    int w16 = (tid >> 6) * 16;
    int mr = lane & 15;
    int q = lane >> 4;
    int q8 = q * 8;
    int n0 = blockIdx.x * 64;
    const u16* wb = wch + (size_t)dir * 1024 * 256;

    // accumulator init from fragment-order xgates (same tile/thread mapping)
    int gp = dir * 8 + p;
    size_t xoff = ((size_t)(gp * 64 + (rb & 63)) * 16 + blockIdx.x) * 4096 + (size_t)tid * 16;
    u16 tmp[16];
    *(uint4*)tmp = *(const uint4*)(xgates + xoff);
    *(uint4*)(tmp + 8) = *(const uint4*)(xgates + xoff + 8);
    f4 acc[4];
#pragma unroll
    for (int nt = 0; nt < 4; ++nt)
#pragma unroll
        for (int r = 0; r < 4; ++r) acc[nt][r] = bf2f(tmp[nt * 4 + r]);

    for (int kt = 0; kt < 4; ++kt) {
#pragma unroll
        for (int i = 0; i < 2; ++i) {
            int c = tid + i * 256;
            int row = c >> 3;
            int cc = (c & 7) * 8;
            *(uint4*)&As[row * 72 + cc] = *(const uint4*)(hin + hoffs[row] + kt * 64 + cc);
            *(uint4*)&Bs[row * 72 + cc] =
                *(const uint4*)(wb + (size_t)(n0 + row) * 256 + kt * 64 + cc);
        }
        __syncthreads();
#pragma unroll
        for (int kk = 0; kk < 64; kk += 32) {
            bf8 af = *(const bf8*)&As[(w16 + mr) * 72 + kk + q8];
#pragma unroll
            for (int nt = 0; nt < 4; ++nt) {
                bf8 bg = *(const bf8*)&Bs[(nt * 16 + mr) * 72 + kk + q8];
                acc[nt] = __builtin_amdgcn_mfma_f32_16x16x32_bf16(af, bg, acc[nt], 0, 0, 0);
            }
        }
        __syncthreads();
    }

    // epilogue: LSTM pointwise, thread-local (acc[nt] = gate nt of j)
    int j = blockIdx.x * 16 + mr;
#pragma unroll
    for (int r = 0; r < 4; ++r) {
        int m = w16 + q * 4 + r;
        if (base + m < cnt) {
            int span = spans_s[m];
            float gi = acc[0][r], gf = acc[1][r], gg = acc[2][r], go = acc[3][r];
            int si = (dir * 4096 + span) * H_ + j;
            float c = cbuf[si];
            float cn = sigm(gf) * c + sigm(gi) * tanhf(gg);
            float h = sigm(go) * tanhf(cn);
            cbuf[si] = cn;
            hout[si] = f2bf(h);
            pooled[span * 512 + dir * H_ + j] += h;
        }
    }
}

// ---------------- final scores: MFMA GEMM [4096x512] x [512x64] ----------------
__global__ __launch_bounds__(256) void scores_mfma(const float* __restrict__ pooled,
                                                   const float* __restrict__ emb,
                                                   float* __restrict__ out) {
    int g = blockIdx.x;             // 64 blocks x 64 rows
    int tid = threadIdx.x;

    __shared__ u16 As[64 * 72];
    __shared__ u16 Bs[64 * 72];

    int lane = tid & 63;
    int w16 = (tid >> 6) * 16;
    int mr = lane & 15;
    int q = lane >> 4;
    int q8 = q * 8;

    f4 acc[4];
    f4 zed = {0.f, 0.f, 0.f, 0.f};
#pragma unroll
    for (int i = 0; i < 4; ++i) acc[i] = zed;

    for (int kt = 0; kt < 8; ++kt) {
#pragma unroll
        for (int i = 0; i < 2; ++i) {
            int c = tid + i * 256;
            int row = c >> 3;
            int cc = (c & 7) * 8;
            const float4* a = (const float4*)(pooled + (size_t)(g * 64 + row) * 512 + kt * 64 + cc);
            float4 v0 = a[0], v1 = a[1];
            ushort4 o0, o1;
            o0.x = f2bf(v0.x); o0.y = f2bf(v0.y); o0.z = f2bf(v0.z); o0.w = f2bf(v0.w);
            o1.x = f2bf(v1.x); o1.y = f2bf(v1.y); o1.z = f2bf(v1.z); o1.w = f2bf(v1.w);
            *(ushort4*)&As[row * 72 + cc] = o0;
            *(ushort4*)&As[row * 72 + cc + 4] = o1;
            const float4* b = (const float4*)(emb + (size_t)row * 512 + kt * 64 + cc);
            float4 w0 = b[0], w1 = b[1];
            ushort4 p0, p1;
            p0.x = f2bf(w0.x); p0.y = f2bf(w0.y); p0.z = f2bf(w0.z); p0.w = f2bf(w0.w);
            p1.x = f2bf(w1.x); p1.y = f2bf(w1.y); p1.z = f2bf(w1.z); p1.w = f2bf(w1.w);
            *(ushort4*)&Bs[row * 72 + cc] = p0;
            *(ushort4*)&Bs[row * 72 + cc + 4] = p1;
        }
        __syncthreads();
#pragma unroll
        for (int kk = 0; kk < 64; kk += 32) {
            bf8 af = *(const bf8*)&As[(w16 + mr) * 72 + kk + q8];
#pragma unroll
            for (int nt = 0; nt < 4; ++nt) {
                bf8 bg = *(const bf8*)&Bs[(nt * 16 + mr) * 72 + kk + q8];
                acc[nt] = __builtin_amdgcn_mfma_f32_16x16x32_bf16(af, bg, acc[nt], 0, 0, 0);
            }
        }
        __syncthreads();
    }

#pragma unroll
    for (int nt = 0; nt < 4; ++nt) {
#pragma unroll
        for (int r = 0; r < 4; ++r) {
            int m = g * 64 + w16 + q * 4 + r;
            int n = nt * 16 + mr;
            out[(size_t)m * 64 + n] = acc[nt][r];
        }
    }
}

// ---------------- launch ----------------

extern "C" void kernel_launch(void* const* d_in, const int* in_sizes, int n_in,
                              void* d_out, int out_size, void* d_ws, size_t ws_size,
                              hipStream_t stream) {
    const float* lstm_repr = (const float*)d_in[0];
    const float* W_ih_f = (const float*)d_in[1];
    const float* W_hh_f = (const float*)d_in[2];
    const float* b_f    = (const float*)d_in[3];
    const float* W_ih_b = (const float*)d_in[4];
    const float* W_hh_b = (const float*)d_in[5];
    const float* b_b    = (const float*)d_in[6];
    const float* slot_emb = (const float*)d_in[7];
    const int* bio      = (const int*)d_in[8];
    float* out = (float*)d_out;

    char* ws = (char*)d_ws;
    // layout (bytes):
    u16*  xg     = (u16*)(ws + 0);              // 4096*8*512 bf16      =  33,554,432
    u16*  xgates = (u16*)(ws + 33554432);       // 16*4096*1024 bf16    = 134,217,728
    u16*  wcx    = (u16*)(ws + 167772160);      // 2*1024*512 bf16      =   2,097,152
    u16*  wch    = (u16*)(ws + 169869312);      // 2*1024*256 bf16      =   1,048,576
    float* bc    = (float*)(ws + 170917888);    // 2*1024 f32           =       8,192
    int*  tok    = (int*)(ws + 170926080);      // 4096*8 i32           =     131,072
    int*  lenb   = (int*)(ws + 171057152);      // 4096 i32             =      16,384
    int*  lists  = (int*)(ws + 171073536);      // 8*4096 i32           =     131,072
    int*  counts = (int*)(ws + 171204608);      // 8 i32 (padded 256)
    float* pooled= (float*)(ws + 171204864);    // 4096*512 f32         =   8,388,608  (zeroed)
    float* cbuf  = (float*)(ws + 179593472);    // 2*4096*256 f32       =   8,388,608  (zeroed)
    u16*  hbf    = (u16*)(ws + 187982080);      // 2x [2*4096*256] bf16 =   8,388,608  (zeroed)
    // total: 196,370,688 bytes (ws = 256 MiB)
    u16* hb[2] = { hbf, hbf + 2 * 4096 * 256 };

    build_wc2<<<6152, 256, 0, stream>>>(W_ih_f, W_hh_f, W_ih_b, W_hh_b, b_f, b_b,
                                        wcx, wch, bc);
    // zero pooled + cbuf + hbf(both) : 25,165,824 B = 1,572,864 uint4
    zero_ws<<<6144, 256, 0, stream>>>((uint4*)pooled, 1572864);
    pack_spans2<<<64, 512, 0, stream>>>(bio, tok, lenb);
    build_lists<<<1, 256, 0, stream>>>(lenb, lists, counts);
    conv_gather<<<32768, 64, 0, stream>>>(lstm_repr, tok, lenb, xg);

    // parallel x-part gate precompute for all (dir, p) row groups
    xgate_gemm<<<dim3(16, 1024), 256, 0, stream>>>(xg, wcx, bc, lists, counts, lenb,
                                                   xgates);

    for (int p = 0; p < 8; ++p) {
        fused_step<<<dim3(16, 128), 256, 0, stream>>>(xgates, hb[p & 1], hb[1 - (p & 1)],
                                                      wch, lists, counts, cbuf, pooled, p);
    }
    scores_mfma<<<64, 256, 0, stream>>>(pooled, slot_emb, out);
}